// Round 11
// baseline (85.863 us; speedup 1.0000x reference)
//
#include <hip/hip_runtime.h>
#include <math.h>

#define B 4
#define N 4096
#define M 8192
#define C 64
#define NB 2048
#define XMIN (-64.0f)
#define INV_BW 16.0f   // bucket width 0.0625
#define CUT 10.0f      // truncation at exp(-10): err ~0.008 << 0.43
#define QG 16          // queries per group == MFMA M

typedef __attribute__((ext_vector_type(8))) short short8;   // 8 bf16
typedef __attribute__((ext_vector_type(4))) float f32x4;

__device__ __forceinline__ int bucket_of(float v) {
    int k = (int)floorf((v - XMIN) * INV_BW);
    return min(max(k, 0), NB - 1);
}

__device__ __forceinline__ unsigned short f2bf(float f) {   // RNE fp32->bf16
    unsigned int u = __float_as_uint(f);
    return (unsigned short)((u + 0x7FFF + ((u >> 16) & 1)) >> 16);
}

// Blocks 0..3: bin points (batch b) -> bucket_start, xs, islot.
// Blocks 4..7: bin queries (batch b) -> qcs/qis. Wave-shuffle scan.
__global__ __launch_bounds__(1024) void bin_kernel(
    const float* __restrict__ xz, const float* __restrict__ x,
    int* __restrict__ bucket_start,    // [B][NB+1]
    float* __restrict__ xs,            // [B*M + slack] sorted point coords
    int* __restrict__ islot,           // [B][M] original m -> sorted slot
    float* __restrict__ qcs,           // [B][N] sorted query coords
    int* __restrict__ qis)             // [B][N] sorted slot -> original n
{
    const int t    = threadIdx.x;
    const int lane = t & 63;
    const int w    = t >> 6;

    __shared__ int hist[NB];
    __shared__ int run[NB];
    __shared__ int wsum[16];
    const bool isQ = blockIdx.x >= 4;
    const int  b   = blockIdx.x & 3;
    const int  PT  = isQ ? (N / 1024) : (M / 1024);
    const float* src = isQ ? (x + b * N) : (xz + b * M);

    hist[t] = 0; hist[t + 1024] = 0;
    __syncthreads();

    float pv[8]; int pk[8];
    for (int j = 0; j < PT; ++j) {
        float v = src[j * 1024 + t];
        pv[j] = v; pk[j] = bucket_of(v);
        atomicAdd(&hist[pk[j]], 1);
    }
    __syncthreads();

    const int h0 = hist[2 * t], h1 = hist[2 * t + 1];
    const int tot = h0 + h1;
    int s = tot;
    #pragma unroll
    for (int off = 1; off < 64; off <<= 1) {
        int up = __shfl_up(s, off, 64);
        if (lane >= off) s += up;
    }
    if (lane == 63) wsum[w] = s;
    __syncthreads();
    int woff = 0;
    for (int i = 0; i < w; ++i) woff += wsum[i];
    const int excl = woff + s - tot;

    run[2 * t]     = excl;
    run[2 * t + 1] = excl + h0;
    if (!isQ) {
        bucket_start[b * (NB + 1) + 2 * t]     = excl;
        bucket_start[b * (NB + 1) + 2 * t + 1] = excl + h0;
        if (t == 1023) bucket_start[b * (NB + 1) + NB] = woff + s;  // == M
    }
    __syncthreads();

    if (!isQ) {
        for (int j = 0; j < PT; ++j) {
            int slot = atomicAdd(&run[pk[j]], 1);
            xs[b * M + slot]            = pv[j];
            islot[b * M + j * 1024 + t] = slot;
        }
    } else {
        for (int j = 0; j < PT; ++j) {
            int slot = atomicAdd(&run[pk[j]], 1);
            qcs[b * N + slot] = pv[j];
            qis[b * N + slot] = j * 1024 + t;
        }
    }
}

// 512 blocks: permute z [B,C,M] into bf16 sorted-row layout zs[slot][C].
__global__ __launch_bounds__(1024) void permz_kernel(
    const float* __restrict__ z, const int* __restrict__ islot,
    unsigned short* __restrict__ zs)   // [B*M + slack][C] bf16
{
    const int t  = threadIdx.x;
    const int b  = blockIdx.x >> 7;
    const int m0 = (blockIdx.x & 127) * 64;
    __shared__ float tile[64][65];
    __shared__ int slot_s[64];

    const int m = t & 63;
    #pragma unroll
    for (int k = 0; k < 4; ++k) {
        int c = (t >> 6) + 16 * k;
        tile[c][m] = z[((size_t)b * C + c) * M + m0 + m];   // coalesced in m
    }
    if (t < 64) slot_s[t] = islot[b * M + m0 + t];
    __syncthreads();

    const int j  = t >> 4;
    const int c4 = t & 15;
    ushort4 v4;
    v4.x = f2bf(tile[c4 * 4 + 0][j]);
    v4.y = f2bf(tile[c4 * 4 + 1][j]);
    v4.z = f2bf(tile[c4 * 4 + 2][j]);
    v4.w = f2bf(tile[c4 * 4 + 3][j]);
    ((ushort4*)zs)[((size_t)b * M + slot_s[j]) * 16 + c4] = v4;
}

// One block per 16 sorted queries; 4 waves; mfma_f32_16x16x32_bf16.
// Double-buffered LDS staging: chunk i+1's global_load_lds is issued right
// after barrier_i, so it has the whole iteration (weights+MFMA) in flight
// before barrier_{i+1} drains it. Group index swizzled for load balance.
__global__ __launch_bounds__(256) void gather_kernel(
    const float* __restrict__ log_scale,
    const int* __restrict__ bucket_start,
    const float* __restrict__ xs,
    const float* __restrict__ qcs,
    const int* __restrict__ qis,
    const unsigned short* __restrict__ zs,   // [B*M + slack][C] bf16
    float* __restrict__ out)                 // [B][N][C]
{
    const int t    = threadIdx.x;
    const int lane = t & 63;
    const int w    = t >> 6;            // wave 0..3 -> channels w*16..+15
    const int quad = lane >> 4;         // 0..3
    const int low4 = lane & 15;
    const int b  = blockIdx.x >> 8;     // 256 groups per batch
    // load-balance swizzle: bijective mod 256 so each CU gets a density mix
    const int g0 = (((blockIdx.x & 255) * 167) & 255) * QG;

    __shared__ unsigned short zr[2][64 * 64];   // 16 KB double-buffered rows
    __shared__ unsigned short wl[2][QG][72];    // 4.5 KB padded weight tiles
    __shared__ float qcS[QG];
    __shared__ int   qiS[QG];

    const float ls   = log_scale[0];
    const float coef = -0.5f * __expf(-2.0f * ls);   // negative
    const float R    = sqrtf(CUT / (-coef));

    if (t < QG) {
        qcS[t] = qcs[b * N + g0 + t];
        qiS[t] = qis[b * N + g0 + t];
    }
    __syncthreads();

    float xmin = qcS[0], xmax = qcS[0];
    #pragma unroll
    for (int j = 1; j < QG; ++j) {
        xmin = fminf(xmin, qcS[j]);
        xmax = fmaxf(xmax, qcS[j]);
    }
    const int s0 = bucket_start[b * (NB + 1) + bucket_of(xmin - R)];
    const int s1 = bucket_start[b * (NB + 1) + bucket_of(xmax + R) + 1];
    const int e0 = s0 & ~63;                 // 64-aligned window; M%64==0
    const int e1 = (s1 + 63) & ~63;          // extra slots are real points

    // weight-phase mapping: lane computes query qw, point group pg (x4)
    const int qw = w * 4 + (lane >> 4);
    const int pg = lane & 15;
    const float qv = qcS[qw];

    f32x4 acc = {0.f, 0.f, 0.f, 0.f};

    const float* xsb = xs + b * M;
    const unsigned short* zsb = zs + (size_t)b * M * C;

    // stage rows cs..cs+63 into zr[bb]: 2 loads/wave, 1KB each, coalesced
    auto stage = [&](int cs, int bb) {
        #pragma unroll
        for (int r = 0; r < 2; ++r) {
            const unsigned short* gp =
                zsb + ((size_t)cs + (w * 2 + r) * 8 + (lane >> 3)) * C + (lane & 7) * 8;
            unsigned short* lp = &zr[bb][(w * 2 + r) * 512];  // wave-uniform base
            __builtin_amdgcn_global_load_lds(
                (const __attribute__((address_space(1))) void*)gp,
                (__attribute__((address_space(3))) void*)lp, 16, 0, 0);
        }
    };

    if (e0 < e1) stage(e0, 0);               // prologue

    int buf = 0;
    for (int cs = e0; cs < e1; cs += 64, buf ^= 1) {
        // block-shared weights for THIS chunk (VALU; overlaps in-flight stage)
        {
            const float4 xp4 = *(const float4*)(xsb + cs + pg * 4);
            float d0 = qv - xp4.x, d1 = qv - xp4.y;
            float d2 = qv - xp4.z, d3 = qv - xp4.w;
            ushort4 wv;
            wv.x = f2bf(__expf(coef * d0 * d0));
            wv.y = f2bf(__expf(coef * d1 * d1));
            wv.z = f2bf(__expf(coef * d2 * d2));
            wv.w = f2bf(__expf(coef * d3 * d3));
            *(ushort4*)&wl[buf][qw][pg * 4] = wv;
        }
        __syncthreads();                 // drains stage(cs); wl[buf] visible
        if (cs + 64 < e1) stage(cs + 64, buf ^ 1);   // next chunk in flight
        // A = weights via b128 (padded rows), B = zr scalar u16, 2 MFMA
        #pragma unroll
        for (int kh = 0; kh < 2; ++kh) {
            short8 afrag = *(const short8*)&wl[buf][low4][kh * 32 + quad * 8];
            short8 bfrag;
            #pragma unroll
            for (int j = 0; j < 8; ++j) {
                const int p = kh * 32 + quad * 8 + j;
                bfrag[j] = (short)zr[buf][p * 64 + w * 16 + low4];
            }
            acc = __builtin_amdgcn_mfma_f32_16x16x32_bf16(afrag, bfrag, acc, 0, 0, 0);
        }
    }

    // D: row(query) = quad*4 + r, col(channel local) = low4
    #pragma unroll
    for (int r = 0; r < 4; ++r) {
        const int q = quad * 4 + r;
        out[((size_t)b * N + qiS[q]) * C + w * 16 + low4] = acc[r];
    }
}

extern "C" void kernel_launch(void* const* d_in, const int* in_sizes, int n_in,
                              void* d_out, int out_size, void* d_ws, size_t ws_size,
                              hipStream_t stream) {
    const float* xz = (const float*)d_in[0];  // [B,M,1]
    const float* z  = (const float*)d_in[1];  // [B,C,M]
    const float* x  = (const float*)d_in[2];  // [B,N,1]
    const float* ls = (const float*)d_in[3];  // scalar
    float* out = (float*)d_out;               // [B,N,C]

    char* ws = (char*)d_ws;
    size_t off = 0;
    auto alloc = [&](size_t bytes) { void* p = ws + off; off += (bytes + 255) & ~size_t(255); return p; };

    unsigned short* zs = (unsigned short*)alloc(((size_t)B * M + 64) * C * sizeof(unsigned short)); // ~4.2MB
    float* xs    = (float*)alloc(((size_t)B * M + 64) * sizeof(float));
    int*   islot = (int*)alloc((size_t)B * M * sizeof(int));
    float* qcs   = (float*)alloc((size_t)B * N * sizeof(float));
    int*   qis   = (int*)alloc((size_t)B * N * sizeof(int));
    int*   bst   = (int*)alloc((size_t)B * (NB + 1) * sizeof(int));

    bin_kernel<<<8, 1024, 0, stream>>>(xz, x, bst, xs, islot, qcs, qis);
    permz_kernel<<<512, 1024, 0, stream>>>(z, islot, zs);
    gather_kernel<<<B * (N / QG), 256, 0, stream>>>(ls, bst, xs, qcs, qis, zs, out);
}